// Round 9
// baseline (183.208 us; speedup 1.0000x reference)
//
#include <hip/hip_runtime.h>
#include <hip/hip_bf16.h>

#define NN 6144
#define CAP 128

typedef short bf8 __attribute__((ext_vector_type(8)));
typedef float f4 __attribute__((ext_vector_type(4)));

__device__ inline unsigned short f2bf(float x) {
  union { float f; unsigned u; } v; v.f = x;
  unsigned r = v.u + 0x7fff + ((v.u >> 16) & 1);
  return (unsigned short)(r >> 16);
}
__device__ inline float bf2f(unsigned short b) {
  union { float f; unsigned u; } v; v.u = ((unsigned)b) << 16;
  return v.f;
}

// async global->LDS, 16B per lane (wave-uniform LDS base + lane*16)
__device__ inline void gload16(const float* g, void* l) {
  __builtin_amdgcn_global_load_lds(
      (const __attribute__((address_space(1))) void*)g,
      (__attribute__((address_space(3))) void*)l, 16, 0, 0);
}

// ================================================================ device bodies

// ---- sparsify via LDS streaming: bid in [0, 3072), smem: 48KB (12KB/wave)
__device__ void dev_sparsify(int bid, int tid, char* smem,
    const float* __restrict__ A0, const float* __restrict__ A1,
    int* __restrict__ colsB, float* __restrict__ valsB, int* __restrict__ cntB) {
  const int br = bid >= 1536;
  const int bb = br ? bid - 1536 : bid;
  const float* __restrict__ A = br ? A1 : A0;
  int* cols = colsB + (size_t)br * NN * CAP;
  float* vals = valsB + (size_t)br * NN * CAP;
  int* cnt = cntB + br * NN;
  const int wv = tid >> 6, lane = tid & 63;
  const int row = bb * 4 + wv;
  const float* __restrict__ arow = A + (size_t)row * NN;
  char* buf = smem + wv * 12288;
  int base = 0;
  const int rbase = row * CAP;
  for (int half = 0; half < 2; ++half) {
    // issue 12KB of async loads (12 outstanding x 1KB) -- high MLP, zero VGPR
#pragma unroll
    for (int i = 0; i < 12; ++i)
      gload16(arow + half * 3072 + i * 256 + lane * 4, buf + i * 1024);
    asm volatile("s_waitcnt vmcnt(0)" ::: "memory");
    __builtin_amdgcn_sched_barrier(0);
#pragma unroll
    for (int i = 0; i < 12; ++i) {
      f4 v = *(f4*)(buf + i * 1024 + lane * 16);
      const int it = half * 12 + i;
      float xs[4] = {v[0], v[1], v[2], v[3]};
      unsigned long long m[4];
#pragma unroll
      for (int q = 0; q < 4; ++q) m[q] = __ballot(xs[q] != 0.0f);
      int off0 = base;
      int off1 = off0 + __popcll(m[0]);
      int off2 = off1 + __popcll(m[1]);
      int off3 = off2 + __popcll(m[2]);
      base = off3 + __popcll(m[3]);
      int offs[4] = {off0, off1, off2, off3};
      unsigned long long lmask = (1ull << lane) - 1ull;
#pragma unroll
      for (int q = 0; q < 4; ++q) {
        if (xs[q] != 0.0f) {
          int idx = offs[q] + __popcll(m[q] & lmask);
          if (idx < CAP) {
            cols[rbase + idx] = (it * 64 + lane) * 4 + q;
            vals[rbase + idx] = xs[q];
          }
        }
      }
    }
  }
  if (lane == 0) cnt[row] = base < CAP ? base : CAP;
}

// ---- weights -> hi/lo (+T): cb in [0, 1280)
__device__ void dev_convw(int cb, int tid,
    const float* __restrict__ W11, const float* __restrict__ W21,
    const float* __restrict__ W12, const float* __restrict__ W22,
    short* __restrict__ W1h, short* __restrict__ W1l,
    short* __restrict__ W1th, short* __restrict__ W1tl,
    short* __restrict__ W2h, short* __restrict__ W2l,
    short* __restrict__ W2th, short* __restrict__ W2tl) {
  const int S1 = 512 * 256, S2 = 256 * 128;
  int i = cb * 256 + tid;
  if (i < 2 * S1) {
    int br = i >= S1;
    int idx = br ? i - S1 : i;
    float x = (br ? W21 : W11)[idx];
    unsigned short h = f2bf(x), l = f2bf(x - bf2f(h));
    int r = idx / 256, c = idx % 256;
    size_t o = (size_t)br * S1;
    W1h[o + idx] = (short)h; W1l[o + idx] = (short)l;
    W1th[o + c * 512 + r] = (short)h; W1tl[o + c * 512 + r] = (short)l;
  } else {
    int i2 = i - 2 * S1;
    if (i2 >= 2 * S2) return;
    int br = i2 >= S2;
    int idx = br ? i2 - S2 : i2;
    float x = (br ? W22 : W12)[idx];
    unsigned short h = f2bf(x), l = f2bf(x - bf2f(h));
    int r = idx / 128, c = idx % 128;
    size_t o = (size_t)br * S2;
    W2h[o + idx] = (short)h; W2l[o + idx] = (short)l;
    W2th[o + c * 256 + r] = (short)h; W2tl[o + c * 256 + r] = (short)l;
  }
}

// ---- X -> bf16 hi: xb in [0, 6144)
__device__ void dev_convX(int xb, int tid,
    const float* __restrict__ X0, const float* __restrict__ X1,
    short* __restrict__ XhB) {
  const int br = xb >= 3072;
  const int b = br ? xb - 3072 : xb;
  const float* __restrict__ in = br ? X1 : X0;
  short* hi = XhB + (size_t)br * NN * 512;
  int i = b * 256 + tid;
  float4 v = *(const float4*)&in[i * 4];
  short4 h;
  h.x = (short)f2bf(v.x);
  h.y = (short)f2bf(v.y);
  h.z = (short)f2bf(v.z);
  h.w = (short)f2bf(v.w);
  *(short4*)&hi[i * 4] = h;
}

// ---- fvec (layer 1, D=256, bf16 input): fb in [0, 3072)
__device__ void dev_fvec256(int fb, int tid,
    const short* __restrict__ HB, const float* __restrict__ v10,
    const float* __restrict__ v20, const float* __restrict__ v11,
    const float* __restrict__ v21, float* __restrict__ f1B, float* __restrict__ f2B) {
  const int br = fb >= 1536;
  const int bb = br ? fb - 1536 : fb;
  const short* H = HB + (size_t)br * NN * 256;
  const float* v1 = br ? v11 : v10;
  const float* v2 = br ? v21 : v20;
  float* f1 = f1B + br * NN;
  float* f2 = f2B + br * NN;
  int row = (bb * 256 + tid) >> 6;
  int lane = tid & 63;
  const short* hp = H + (size_t)row * 256 + lane * 4;
  float s1 = 0.f, s2 = 0.f;
#pragma unroll
  for (int e = 0; e < 4; ++e) {
    float h = bf2f((unsigned short)hp[e]);
    s1 += h * v1[lane * 4 + e];
    s2 += h * v2[lane * 4 + e];
  }
#pragma unroll
  for (int o = 32; o; o >>= 1) {
    s1 += __shfl_xor(s1, o);
    s2 += __shfl_xor(s2, o);
  }
  if (lane == 0) { f1[row] = s1; f2[row] = s2; }
}

// ---- split-bf16 MFMA GEMM (NT) tile body; smem >= (ALO?4:3)*5120 bytes
#define GS 40
#define MFMA_BF16 __builtin_amdgcn_mfma_f32_16x16x32_bf16

template <bool ALO, int EPI>  // EPI 0: f32, 1: bf16-hi, 2: hi+lo
__device__ void dev_gemm(int bx, int by, int br, int tid, char* smemc,
    const short* __restrict__ AhB, const short* __restrict__ AlB, size_t sA,
    const short* __restrict__ BhB, const short* __restrict__ BlB, size_t sB,
    float* __restrict__ CfB, short* __restrict__ ChB, short* __restrict__ ClB,
    size_t sC, int K, int Nn) {
  short* sAh = (short*)smemc;
  short* sBh = sAh + 64 * GS;
  short* sBl = sBh + 64 * GS;
  short* sAl = sBl + 64 * GS;  // used only if ALO
  const short* Ahg = AhB + br * sA;
  const short* Bhg = BhB + br * sB;
  const short* Blg = BlB + br * sB;
  const int bm = bx * 64, bn = by * 64;
  const int t = tid;
  const int lane = t & 63, w = t >> 6;
  const int wm = (w & 1) * 32, wn = (w >> 1) * 32;
  const int fr = lane & 15, fq = lane >> 4;
  const int srow = t >> 2, sk = (t & 3) * 8;

  f4 acc[2][2] = {};

  for (int k0 = 0; k0 < K; k0 += 32) {
    const size_t aoff = (size_t)(bm + srow) * K + k0 + sk;
    const size_t boff = (size_t)(bn + srow) * K + k0 + sk;
    bf8 vah = *(const bf8*)&Ahg[aoff];
    bf8 vbh = *(const bf8*)&Bhg[boff];
    bf8 vbl = *(const bf8*)&Blg[boff];
    bf8 val_;
    if constexpr (ALO) val_ = *(const bf8*)&(AlB + br * sA)[aoff];
    __syncthreads();
    *(bf8*)&sAh[srow * GS + sk] = vah;
    *(bf8*)&sBh[srow * GS + sk] = vbh;
    *(bf8*)&sBl[srow * GS + sk] = vbl;
    if constexpr (ALO) *(bf8*)&sAl[srow * GS + sk] = val_;
    __syncthreads();

    bf8 ah[2], al[2], bh[2], bl[2];
#pragma unroll
    for (int i = 0; i < 2; ++i) {
      ah[i] = *(bf8*)&sAh[(wm + i * 16 + fr) * GS + fq * 8];
      bh[i] = *(bf8*)&sBh[(wn + i * 16 + fr) * GS + fq * 8];
      bl[i] = *(bf8*)&sBl[(wn + i * 16 + fr) * GS + fq * 8];
      if constexpr (ALO) al[i] = *(bf8*)&sAl[(wm + i * 16 + fr) * GS + fq * 8];
    }
#pragma unroll
    for (int mi = 0; mi < 2; ++mi)
#pragma unroll
      for (int ni = 0; ni < 2; ++ni) {
        acc[mi][ni] = MFMA_BF16(ah[mi], bh[ni], acc[mi][ni], 0, 0, 0);
        acc[mi][ni] = MFMA_BF16(ah[mi], bl[ni], acc[mi][ni], 0, 0, 0);
        if constexpr (ALO) acc[mi][ni] = MFMA_BF16(al[mi], bh[ni], acc[mi][ni], 0, 0, 0);
      }
  }

  float* Cf = CfB ? CfB + br * sC : nullptr;
  short* Ch = ChB ? ChB + br * sC : nullptr;
  short* Cl = ClB ? ClB + br * sC : nullptr;
#pragma unroll
  for (int mi = 0; mi < 2; ++mi)
#pragma unroll
    for (int ni = 0; ni < 2; ++ni) {
      int cidx = bn + wn + ni * 16 + fr;
#pragma unroll
      for (int r = 0; r < 4; ++r) {
        size_t off = (size_t)(bm + wm + mi * 16 + fq * 4 + r) * Nn + cidx;
        float x = acc[mi][ni][r];
        if constexpr (EPI == 0) Cf[off] = x;
        if constexpr (EPI >= 1) {
          unsigned short h = f2bf(x);
          Ch[off] = (short)h;
          if constexpr (EPI == 2) Cl[off] = (short)f2bf(x - bf2f(h));
        }
      }
    }
}

// ---- spmm body (D=128, bf16 in/out, MLP-8): sb in [0, 3072)
__device__ void dev_spmm128(int sb, int tid,
    const int* __restrict__ colsB, const float* __restrict__ cvalsB,
    const int* __restrict__ cntB, const short* __restrict__ HinB,
    short* __restrict__ HhB) {
  const int br = sb >= 1536;
  const int bb = br ? sb - 1536 : sb;
  const int* cols = colsB + (size_t)br * NN * CAP;
  const float* cvals = cvalsB + (size_t)br * NN * CAP;
  const int* cnt = cntB + br * NN;
  const short* Hin = HinB + (size_t)br * NN * 128;
  int row = (bb * 256 + tid) >> 6;
  int lane = tid & 63;
  int c = cnt[row];
  const int base = row * CAP;
  float cv0 = 0.f, cv1 = 0.f;
  int j0 = 0, j1 = 0;
  if (lane < c) { j0 = cols[base + lane]; cv0 = cvals[base + lane]; }
  if (64 + lane < c) { j1 = cols[base + 64 + lane]; cv1 = cvals[base + 64 + lane]; }
  float2 acc = make_float2(0.f, 0.f);
  for (int k = 0; k < c; k += 8) {
    unsigned hv[8]; float cv[8];
#pragma unroll
    for (int u = 0; u < 8; ++u) {
      int kk = k + u;
      if (kk < c) {
        int jj = (kk & 64) ? j1 : j0;
        float cc = (kk & 64) ? cv1 : cv0;
        int j = __shfl(jj, kk & 63);
        cv[u] = __shfl(cc, kk & 63);
        hv[u] = *(const unsigned*)&Hin[(size_t)j * 128 + lane * 2];
      }
    }
#pragma unroll
    for (int u = 0; u < 8; ++u) {
      if (k + u < c) {
        acc.x += cv[u] * bf2f((unsigned short)(hv[u] & 0xffff));
        acc.y += cv[u] * bf2f((unsigned short)(hv[u] >> 16));
      }
    }
  }
  size_t o = (size_t)br * NN * 128 + (size_t)row * 128 + lane * 2;
  unsigned hw = (unsigned)(unsigned short)f2bf(acc.x) | ((unsigned)f2bf(acc.y) << 16);
  *(unsigned*)&HhB[o] = hw;
}

// ---- final body: fb in [0, 1536)
__device__ void dev_final(int fb, int tid,
    const float* __restrict__ H1e, const float* __restrict__ H2e,
    const float* __restrict__ mu, float* __restrict__ hf_out,
    float* __restrict__ q_out) {
  int row = (fb * 256 + tid) >> 6;
  int lane = tid & 63;
  float2 h1 = *(const float2*)&H1e[row * 128 + lane * 2];
  float2 h2 = *(const float2*)&H2e[row * 128 + lane * 2];
  float2 hf = make_float2(h1.x + h2.x, h1.y + h2.y);
  *(float2*)&hf_out[row * 128 + lane * 2] = hf;
  float d2[10];
#pragma unroll
  for (int k = 0; k < 10; ++k) {
    float dx = hf.x - mu[k * 128 + lane * 2];
    float dy = hf.y - mu[k * 128 + lane * 2 + 1];
    d2[k] = dx * dx + dy * dy;
  }
#pragma unroll
  for (int k = 0; k < 10; ++k)
#pragma unroll
    for (int o = 32; o; o >>= 1) d2[k] += __shfl_xor(d2[k], o);
  float q[10], s = 0.f;
#pragma unroll
  for (int k = 0; k < 10; ++k) { q[k] = 1.f / (1.f + d2[k]); s += q[k]; }
  float inv = 1.f / s;
  if (lane < 10) q_out[row * 10 + lane] = q[lane] * inv;
}

// ================================================================ kernels

// K0: convw [0,1280) | convX [1280,7424)
__global__ __launch_bounds__(256) void k0_prep(
    const float* W11, const float* W21, const float* W12, const float* W22,
    short* W1h, short* W1l, short* W1th, short* W1tl,
    short* W2h, short* W2l, short* W2th, short* W2tl,
    const float* X0, const float* X1, short* XhB) {
  int bid = blockIdx.x, tid = threadIdx.x;
  if (bid < 1280) dev_convw(bid, tid, W11, W21, W12, W22,
                            W1h, W1l, W1th, W1tl, W2h, W2l, W2th, W2tl);
  else dev_convX(bid - 1280, tid, X0, X1, XhB);
}

// K1: sparsify [0,3072) | GEMM1 [3072,3840)   (GEMM1 hides under sparsify)
__global__ __launch_bounds__(256) void k1_sparsify_gemm1(
    const float* A0, const float* A1, int* colsB, float* valsB, int* cntB,
    const short* Xh, const short* W1th, const short* W1tl, short* H1h) {
  __shared__ char smem[49152];
  int bid = blockIdx.x, tid = threadIdx.x;
  if (bid < 3072) {
    dev_sparsify(bid, tid, smem, A0, A1, colsB, valsB, cntB);
  } else {
    int g = bid - 3072;              // 96 x 4 x 2
    int bx = g % 96, r = g / 96;
    int by = r & 3, brz = r >> 2;
    dev_gemm<false, 1>(bx, by, brz, tid, smem, Xh, nullptr, (size_t)NN * 512,
                       W1th, W1tl, (size_t)512 * 256, nullptr, H1h, nullptr,
                       (size_t)NN * 256, 512, 256);
  }
}

// K2 wrapper: standalone GEMM
template <bool ALO, int EPI>
__global__ __launch_bounds__(256) void gemm_nt(
    const short* AhB, const short* AlB, size_t sA,
    const short* BhB, const short* BlB, size_t sB,
    float* CfB, short* ChB, short* ClB, size_t sC, int K, int Nn) {
  __shared__ char smem[(ALO ? 4 : 3) * 64 * GS * 2];
  dev_gemm<ALO, EPI>(blockIdx.x, blockIdx.y, blockIdx.z, threadIdx.x, smem,
                     AhB, AlB, sA, BhB, BlB, sB, CfB, ChB, ClB, sC, K, Nn);
}

// K3: GEMM2 [0,384) | fvec1 [384,3456)
__global__ __launch_bounds__(256) void k3_gemm2_fvec(
    const short* H1h, const short* W2th, const short* W2tl, short* G1h,
    const float* v111, const float* v112, const float* v211, const float* v212,
    float* f1, float* f2) {
  __shared__ char smem[3 * 64 * GS * 2];
  int bid = blockIdx.x, tid = threadIdx.x;
  if (bid < 384) {
    int bx = bid % 96, r = bid / 96;
    int by = r & 1, br = r >> 1;
    dev_gemm<false, 1>(bx, by, br, tid, smem, H1h, nullptr, (size_t)NN * 256,
                       W2th, W2tl, (size_t)256 * 128, nullptr, G1h, nullptr,
                       (size_t)NN * 128, 256, 128);
  } else {
    dev_fvec256(bid - 384, tid, H1h, v111, v112, v211, v212, f1, f2);
  }
}

// K4/K5: fused GAT softmax + SPMM (MLP-8) + optional next-layer fvec epilogue
template <bool WF32, bool FUSE>
__global__ __launch_bounds__(256) void gatspmm_kernel(
    const int* __restrict__ colsB, const float* __restrict__ avalsB,
    const int* __restrict__ cntB, const float* __restrict__ f1B,
    const float* __restrict__ f2B, float* __restrict__ cvalsB,
    const short* __restrict__ HinB, float* __restrict__ HoutB,
    short* __restrict__ HhB,
    const float* __restrict__ nv10, const float* __restrict__ nv20,
    const float* __restrict__ nv11, const float* __restrict__ nv21,
    float* __restrict__ g1B, float* __restrict__ g2B) {
  const int br = blockIdx.y;
  const int* cols = colsB + (size_t)br * NN * CAP;
  const float* avals = avalsB + (size_t)br * NN * CAP;
  const int* cnt = cntB + br * NN;
  const float* f1 = f1B + br * NN;
  const float* f2 = f2B + br * NN;
  float* cvals = cvalsB + (size_t)br * NN * CAP;
  const short* Hin = HinB + (size_t)br * NN * 128;
  int row = (blockIdx.x * blockDim.x + threadIdx.x) >> 6;
  int lane = threadIdx.x & 63;
  int c = cnt[row];
  float f1i = f1[row];
  const int base = row * CAP;
  float e0 = 0.f, e1 = 0.f;
  int j0 = 0, j1 = 0;
  {
    int k = lane;
    if (k < c) {
      float a = avals[base + k];
      j0 = cols[base + k];
      float lg = a * (f1i + f2[j0]);
      e0 = expf(1.f / (1.f + expf(-lg)));
    }
    k = 64 + lane;
    if (k < c) {
      float a = avals[base + k];
      j1 = cols[base + k];
      float lg = a * (f1i + f2[j1]);
      e1 = expf(1.f / (1.f + expf(-lg)));
    }
  }
  float s = e0 + e1;
#pragma unroll
  for (int o = 32; o; o >>= 1) s += __shfl_xor(s, o);
  float inv = (s == 0.f) ? 1.f : 1.f / s;
  if (lane < c) cvals[base + lane] = e0 * inv;
  if (64 + lane < c) cvals[base + 64 + lane] = e1 * inv;

  float2 acc = make_float2(0.f, 0.f);
  for (int k = 0; k < c; k += 8) {
    unsigned hv[8]; float cv[8];
#pragma unroll
    for (int u = 0; u < 8; ++u) {
      int kk = k + u;
      if (kk < c) {
        int jj = (kk & 64) ? j1 : j0;
        float ee = (kk & 64) ? e1 : e0;
        int j = __shfl(jj, kk & 63);
        cv[u] = __shfl(ee, kk & 63) * inv;
        hv[u] = *(const unsigned*)&Hin[(size_t)j * 128 + lane * 2];
      }
    }
#pragma unroll
    for (int u = 0; u < 8; ++u) {
      if (k + u < c) {
        acc.x += cv[u] * bf2f((unsigned short)(hv[u] & 0xffff));
        acc.y += cv[u] * bf2f((unsigned short)(hv[u] >> 16));
      }
    }
  }
  size_t o = (size_t)br * NN * 128 + (size_t)row * 128 + lane * 2;
  if constexpr (WF32) *(float2*)&HoutB[o] = acc;
  unsigned hw = (unsigned)(unsigned short)f2bf(acc.x) | ((unsigned)f2bf(acc.y) << 16);
  *(unsigned*)&HhB[o] = hw;
  if constexpr (FUSE) {
    const float* w1 = br ? nv11 : nv10;
    const float* w2 = br ? nv21 : nv20;
    float s1 = acc.x * w1[lane * 2] + acc.y * w1[lane * 2 + 1];
    float s2 = acc.x * w2[lane * 2] + acc.y * w2[lane * 2 + 1];
#pragma unroll
    for (int o2 = 32; o2; o2 >>= 1) {
      s1 += __shfl_xor(s1, o2);
      s2 += __shfl_xor(s2, o2);
    }
    if (lane == 0) { g1B[br * NN + row] = s1; g2B[br * NN + row] = s2; }
  }
}

// K6: spmm C2s [0,3072) | final [3072,4608)
__global__ __launch_bounds__(256) void k6_spmm_final(
    const int* colsB, const float* c2v, const int* cntB,
    const short* Hech, short* C2sh,
    const float* H1e, const float* H2e, const float* mu,
    float* hf_out, float* q_out) {
  int bid = blockIdx.x, tid = threadIdx.x;
  if (bid < 3072) dev_spmm128(bid, tid, colsB, c2v, cntB, Hech, C2sh);
  else dev_final(bid - 3072, tid, H1e, H2e, mu, hf_out, q_out);
}

// K7: standalone spmm
__global__ __launch_bounds__(256) void spmm128_kernel(
    const int* colsB, const float* cvalsB, const int* cntB,
    const short* HinB, short* HhB) {
  dev_spmm128(blockIdx.x + blockIdx.y * 1536, threadIdx.x, colsB, cvalsB, cntB, HinB, HhB);
}

// ================================================================ host
extern "C" void kernel_launch(void* const* d_in, const int* in_sizes, int n_in,
                              void* d_out, int out_size, void* d_ws, size_t ws_size,
                              hipStream_t stream) {
  const int D0 = 512, D1 = 256, D2 = 128;
  const int S1 = D0 * D1, S2 = D1 * D2;
  float* out = (float*)d_out;
  const size_t o0 = 0;                       // H_F  [N,128]
  const size_t o1 = o0 + (size_t)NN * 128;   // q    [N,10]
  const size_t o2 = o1 + (size_t)NN * 10;    // H    [N,128]
  const size_t o3 = o2 + (size_t)NN * 128;   // H2   [N,128]
  const size_t o4 = o3 + (size_t)NN * 128;   // X_   [N,512]
  const size_t o5 = o4 + (size_t)NN * 512;   // X_2  [N,512]

  char* w = (char*)d_ws;
  auto alloc = [&](size_t bytes) -> void* {
    void* p = (void*)w;
    w += (bytes + 255) & ~(size_t)255;
    return p;
  };
  int*   cols  = (int*)  alloc((size_t)2 * NN * CAP * 4);
  float* avals = (float*)alloc((size_t)2 * NN * CAP * 4);
  float* c1v   = (float*)alloc((size_t)2 * NN * CAP * 4);
  float* c2v   = (float*)alloc((size_t)2 * NN * CAP * 4);
  int*   cnt   = (int*)  alloc((size_t)2 * NN * 4);
  float* f1    = (float*)alloc((size_t)2 * NN * 4);
  float* f2    = (float*)alloc((size_t)2 * NN * 4);
  float* g1    = (float*)alloc((size_t)2 * NN * 4);
  float* g2    = (float*)alloc((size_t)2 * NN * 4);
  short* Xh    = (short*)alloc((size_t)2 * NN * D0 * 2);
  short* H1h   = (short*)alloc((size_t)2 * NN * D1 * 2);
  short* G1h   = (short*)alloc((size_t)2 * NN * D2 * 2);
  short* H2h   = (short*)alloc((size_t)2 * NN * D2 * 2);
  short* Hech  = (short*)alloc((size_t)2 * NN * D2 * 2);
  short* C2sh  = (short*)alloc((size_t)2 * NN * D2 * 2);
  short* Cth   = (short*)alloc((size_t)2 * NN * D2 * 2);
  short* Uh    = (short*)alloc((size_t)2 * NN * D1 * 2);
  short* Ul    = (short*)alloc((size_t)2 * NN * D1 * 2);
  short* W1h   = (short*)alloc((size_t)2 * S1 * 2);
  short* W1l   = (short*)alloc((size_t)2 * S1 * 2);
  short* W1th  = (short*)alloc((size_t)2 * S1 * 2);
  short* W1tl  = (short*)alloc((size_t)2 * S1 * 2);
  short* W2h   = (short*)alloc((size_t)2 * S2 * 2);
  short* W2l   = (short*)alloc((size_t)2 * S2 * 2);
  short* W2th  = (short*)alloc((size_t)2 * S2 * 2);
  short* W2tl  = (short*)alloc((size_t)2 * S2 * 2);

  const float* A   = (const float*)d_in[0];
  const float* A2  = (const float*)d_in[1];
  const float* X   = (const float*)d_in[2];
  const float* X2  = (const float*)d_in[3];
  const float* W11 = (const float*)d_in[4];
  const float* v111= (const float*)d_in[5];
  const float* v112= (const float*)d_in[6];
  const float* W12 = (const float*)d_in[7];
  const float* v121= (const float*)d_in[8];
  const float* v122= (const float*)d_in[9];
  const float* W21 = (const float*)d_in[10];
  const float* v211= (const float*)d_in[11];
  const float* v212= (const float*)d_in[12];
  const float* W22 = (const float*)d_in[13];
  const float* v221= (const float*)d_in[14];
  const float* v222= (const float*)d_in[15];
  const float* mu  = (const float*)d_in[16];

  const dim3 rows2(NN / 4, 2);

  // K0: convw + convX (small; feeds K1's GEMM branch)
  k0_prep<<<7424, 256, 0, stream>>>(
      W11, W21, W12, W22, W1h, W1l, W1th, W1tl, W2h, W2l, W2th, W2tl, X, X2, Xh);
  // K1: sparsify (LDS-streamed) || GEMM1 (H1 = X @ W11)
  k1_sparsify_gemm1<<<3840, 256, 0, stream>>>(
      A, A2, cols, avals, cnt, Xh, W1th, W1tl, H1h);
  // K3: G1 = H1 @ W12 (2-MFMA) || fvec1
  k3_gemm2_fvec<<<3456, 256, 0, stream>>>(
      H1h, W2th, W2tl, G1h, v111, v112, v211, v212, f1, f2);
  // K4: C1 + H2 = C1 @ G1 (bf16) + fused fvec2 -> g1/g2
  gatspmm_kernel<false, true><<<rows2, 256, 0, stream>>>(
      cols, avals, cnt, f1, f2, c1v, G1h, nullptr, H2h,
      v121, v122, v221, v222, g1, g2);
  // K5: C2 + Henc = C2 @ H2 -> out o2/o3 (f32) + bf16 copy
  gatspmm_kernel<true, false><<<rows2, 256, 0, stream>>>(
      cols, avals, cnt, g1, g2, c2v, H2h, out + o2, Hech,
      nullptr, nullptr, nullptr, nullptr, nullptr, nullptr);
  // K6: C2s = C2 @ Henc || final (H_F + q)
  k6_spmm_final<<<4608, 256, 0, stream>>>(
      cols, c2v, cnt, Hech, C2sh, out + o2, out + o3, mu, out + o0, out + o1);
  // K7: Ct = C1 @ C2s
  spmm128_kernel<<<rows2, 256, 0, stream>>>(cols, c1v, cnt, C2sh, Cth);
  // K8: U = Ct @ W2^T (2-MFMA, out hi+lo)
  gemm_nt<false, 2><<<dim3(NN / 64, D1 / 64, 2), 256, 0, stream>>>(
      Cth, nullptr, (size_t)NN * D2, W2h, W2l, (size_t)S2,
      nullptr, Uh, Ul, (size_t)NN * D1, D2, D1);
  // K9: X_ = U @ W1^T (3-MFMA, f32 -> out o4/o5)
  gemm_nt<true, 0><<<dim3(NN / 64, D0 / 64, 2), 256, 0, stream>>>(
      Uh, Ul, (size_t)NN * D1, W1h, W1l, (size_t)S1,
      out + o4, nullptr, nullptr, (size_t)NN * D0, D1, D0);
}

// Round 10
// 164.273 us; speedup vs baseline: 1.1153x; 1.1153x over previous
//
#include <hip/hip_runtime.h>
#include <hip/hip_bf16.h>

#define NN 6144
#define CAP 128

typedef short bf8 __attribute__((ext_vector_type(8)));
typedef float f4 __attribute__((ext_vector_type(4)));

__device__ inline unsigned short f2bf(float x) {
  union { float f; unsigned u; } v; v.f = x;
  unsigned r = v.u + 0x7fff + ((v.u >> 16) & 1);
  return (unsigned short)(r >> 16);
}
__device__ inline float bf2f(unsigned short b) {
  union { float f; unsigned u; } v; v.u = ((unsigned)b) << 16;
  return v.f;
}

// ================================================================ device bodies

// ---- sparsify (register MLP-6, non-temporal): bid in [0, 3072)
__device__ void dev_sparsify(int bid, int tid,
    const float* __restrict__ A0, const float* __restrict__ A1,
    int* __restrict__ colsB, float* __restrict__ valsB, int* __restrict__ cntB) {
  const int br = bid >= 1536;
  const int bb = br ? bid - 1536 : bid;
  const float* __restrict__ A = br ? A1 : A0;
  int* cols = colsB + (size_t)br * NN * CAP;
  float* vals = valsB + (size_t)br * NN * CAP;
  int* cnt = cntB + br * NN;
  int row = (bb * 256 + tid) >> 6;
  int lane = tid & 63;
  const f4* __restrict__ arow = (const f4*)(A + (size_t)row * NN);
  int base = 0;
  for (int it = 0; it < 24; it += 6) {
    f4 v[6];
#pragma unroll
    for (int u = 0; u < 6; ++u) v[u] = __builtin_nontemporal_load(&arow[(it + u) * 64 + lane]);
#pragma unroll
    for (int u = 0; u < 6; ++u) {
      float xs[4] = {v[u][0], v[u][1], v[u][2], v[u][3]};
      unsigned long long m[4];
#pragma unroll
      for (int q = 0; q < 4; ++q) m[q] = __ballot(xs[q] != 0.0f);
      int off0 = base;
      int off1 = off0 + __popcll(m[0]);
      int off2 = off1 + __popcll(m[1]);
      int off3 = off2 + __popcll(m[2]);
      base = off3 + __popcll(m[3]);
      int offs[4] = {off0, off1, off2, off3};
      unsigned long long lmask = (1ull << lane) - 1ull;
#pragma unroll
      for (int q = 0; q < 4; ++q) {
        if (xs[q] != 0.0f) {
          int idx = offs[q] + __popcll(m[q] & lmask);
          if (idx < CAP) {
            cols[row * CAP + idx] = ((it + u) * 64 + lane) * 4 + q;
            vals[row * CAP + idx] = xs[q];
          }
        }
      }
    }
  }
  if (lane == 0) cnt[row] = base < CAP ? base : CAP;
}

// ---- weights -> hi/lo transposed only: cb in [0, 1280)
__device__ void dev_convw(int cb, int tid,
    const float* __restrict__ W11, const float* __restrict__ W21,
    const float* __restrict__ W12, const float* __restrict__ W22,
    short* __restrict__ W1th, short* __restrict__ W1tl,
    short* __restrict__ W2th, short* __restrict__ W2tl) {
  const int S1 = 512 * 256, S2 = 256 * 128;
  int i = cb * 256 + tid;
  if (i < 2 * S1) {
    int br = i >= S1;
    int idx = br ? i - S1 : i;
    float x = (br ? W21 : W11)[idx];
    unsigned short h = f2bf(x), l = f2bf(x - bf2f(h));
    int r = idx / 256, c = idx % 256;
    size_t o = (size_t)br * S1;
    W1th[o + c * 512 + r] = (short)h; W1tl[o + c * 512 + r] = (short)l;
  } else {
    int i2 = i - 2 * S1;
    if (i2 >= 2 * S2) return;
    int br = i2 >= S2;
    int idx = br ? i2 - S2 : i2;
    float x = (br ? W22 : W12)[idx];
    unsigned short h = f2bf(x), l = f2bf(x - bf2f(h));
    int r = idx / 128, c = idx % 128;
    size_t o = (size_t)br * S2;
    W2th[o + c * 256 + r] = (short)h; W2tl[o + c * 256 + r] = (short)l;
  }
}

// ---- X -> bf16 hi: xb in [0, 6144)
__device__ void dev_convX(int xb, int tid,
    const float* __restrict__ X0, const float* __restrict__ X1,
    short* __restrict__ XhB) {
  const int br = xb >= 3072;
  const int b = br ? xb - 3072 : xb;
  const float* __restrict__ in = br ? X1 : X0;
  short* hi = XhB + (size_t)br * NN * 512;
  int i = b * 256 + tid;
  float4 v = *(const float4*)&in[i * 4];
  short4 h;
  h.x = (short)f2bf(v.x);
  h.y = (short)f2bf(v.y);
  h.z = (short)f2bf(v.z);
  h.w = (short)f2bf(v.w);
  *(short4*)&hi[i * 4] = h;
}

// ---- Wc = W1 @ W2 ([512,256]@[256,128] -> [512,128]) f32 tile GEMM, hi/lo out
// wb in [0, 32): bx = wb&7, by = (wb>>3)&1, br = wb>>4
__device__ void dev_wc2(int wb, int tid, char* smemc,
    const float* __restrict__ W11, const float* __restrict__ W12,
    const float* __restrict__ W21, const float* __restrict__ W22,
    short* __restrict__ Wch, short* __restrict__ Wcl) {
  const int bx = wb & 7, by = (wb >> 3) & 1, br = wb >> 4;
  const float* W1 = br ? W21 : W11;
  const float* W2 = br ? W22 : W12;
  short* Ch = Wch + (size_t)br * 512 * 128;
  short* Cl = Wcl + (size_t)br * 512 * 128;
  float (*As)[68] = (float(*)[68])smemc;
  float (*Bs)[68] = (float(*)[68])(smemc + 16 * 68 * 4);
  const int bm = bx * 64, bn = by * 64;
  const int t = tid;
  const int tm = (t >> 4) * 4, tn = (t & 15) * 4;
  const int la_m = t >> 2, la_k = (t & 3) * 4;
  const int lb_k = t >> 4, lb_n = (t & 15) * 4;
  float acc[4][4] = {};
  for (int k0 = 0; k0 < 256; k0 += 16) {
    float4 a4 = *(const float4*)&W1[(size_t)(bm + la_m) * 256 + k0 + la_k];
    float4 b4 = *(const float4*)&W2[(size_t)(k0 + lb_k) * 128 + bn + lb_n];
    __syncthreads();
    As[la_k + 0][la_m] = a4.x;
    As[la_k + 1][la_m] = a4.y;
    As[la_k + 2][la_m] = a4.z;
    As[la_k + 3][la_m] = a4.w;
    Bs[lb_k][lb_n + 0] = b4.x;
    Bs[lb_k][lb_n + 1] = b4.y;
    Bs[lb_k][lb_n + 2] = b4.z;
    Bs[lb_k][lb_n + 3] = b4.w;
    __syncthreads();
#pragma unroll
    for (int k = 0; k < 16; ++k) {
      float a0 = As[k][tm + 0], a1 = As[k][tm + 1], a2 = As[k][tm + 2], a3 = As[k][tm + 3];
      float b0 = Bs[k][tn + 0], b1 = Bs[k][tn + 1], b2 = Bs[k][tn + 2], b3 = Bs[k][tn + 3];
      acc[0][0] += a0 * b0; acc[0][1] += a0 * b1; acc[0][2] += a0 * b2; acc[0][3] += a0 * b3;
      acc[1][0] += a1 * b0; acc[1][1] += a1 * b1; acc[1][2] += a1 * b2; acc[1][3] += a1 * b3;
      acc[2][0] += a2 * b0; acc[2][1] += a2 * b1; acc[2][2] += a2 * b2; acc[2][3] += a2 * b3;
      acc[3][0] += a3 * b0; acc[3][1] += a3 * b1; acc[3][2] += a3 * b2; acc[3][3] += a3 * b3;
    }
  }
#pragma unroll
  for (int i = 0; i < 4; ++i)
#pragma unroll
    for (int j = 0; j < 4; ++j) {
      float x = acc[i][j];
      size_t off = (size_t)(bm + tm + i) * 128 + bn + tn + j;
      unsigned short h = f2bf(x);
      Ch[off] = (short)h;
      Cl[off] = (short)f2bf(x - bf2f(h));
    }
}

// ---- fvec (layer 1, D=256, bf16 input): fb in [0, 3072)
__device__ void dev_fvec256(int fb, int tid,
    const short* __restrict__ HB, const float* __restrict__ v10,
    const float* __restrict__ v20, const float* __restrict__ v11,
    const float* __restrict__ v21, float* __restrict__ f1B, float* __restrict__ f2B) {
  const int br = fb >= 1536;
  const int bb = br ? fb - 1536 : fb;
  const short* H = HB + (size_t)br * NN * 256;
  const float* v1 = br ? v11 : v10;
  const float* v2 = br ? v21 : v20;
  float* f1 = f1B + br * NN;
  float* f2 = f2B + br * NN;
  int row = (bb * 256 + tid) >> 6;
  int lane = tid & 63;
  const short* hp = H + (size_t)row * 256 + lane * 4;
  float s1 = 0.f, s2 = 0.f;
#pragma unroll
  for (int e = 0; e < 4; ++e) {
    float h = bf2f((unsigned short)hp[e]);
    s1 += h * v1[lane * 4 + e];
    s2 += h * v2[lane * 4 + e];
  }
#pragma unroll
  for (int o = 32; o; o >>= 1) {
    s1 += __shfl_xor(s1, o);
    s2 += __shfl_xor(s2, o);
  }
  if (lane == 0) { f1[row] = s1; f2[row] = s2; }
}

// ---- split-bf16 MFMA GEMM (NT) tile body; smem >= (ALO?4:3)*5120 bytes
#define GS 40
#define MFMA_BF16 __builtin_amdgcn_mfma_f32_16x16x32_bf16

template <bool ALO, int EPI>  // EPI 0: f32, 1: bf16-hi, 2: hi+lo
__device__ void dev_gemm(int bx, int by, int br, int tid, char* smemc,
    const short* __restrict__ AhB, const short* __restrict__ AlB, size_t sA,
    const short* __restrict__ BhB, const short* __restrict__ BlB, size_t sB,
    float* __restrict__ CfB, short* __restrict__ ChB, short* __restrict__ ClB,
    size_t sC, int K, int Nn) {
  short* sAh = (short*)smemc;
  short* sBh = sAh + 64 * GS;
  short* sBl = sBh + 64 * GS;
  short* sAl = sBl + 64 * GS;  // used only if ALO
  const short* Ahg = AhB + br * sA;
  const short* Bhg = BhB + br * sB;
  const short* Blg = BlB + br * sB;
  const int bm = bx * 64, bn = by * 64;
  const int t = tid;
  const int lane = t & 63, w = t >> 6;
  const int wm = (w & 1) * 32, wn = (w >> 1) * 32;
  const int fr = lane & 15, fq = lane >> 4;
  const int srow = t >> 2, sk = (t & 3) * 8;

  f4 acc[2][2] = {};

  for (int k0 = 0; k0 < K; k0 += 32) {
    const size_t aoff = (size_t)(bm + srow) * K + k0 + sk;
    const size_t boff = (size_t)(bn + srow) * K + k0 + sk;
    bf8 vah = *(const bf8*)&Ahg[aoff];
    bf8 vbh = *(const bf8*)&Bhg[boff];
    bf8 vbl = *(const bf8*)&Blg[boff];
    bf8 val_;
    if constexpr (ALO) val_ = *(const bf8*)&(AlB + br * sA)[aoff];
    __syncthreads();
    *(bf8*)&sAh[srow * GS + sk] = vah;
    *(bf8*)&sBh[srow * GS + sk] = vbh;
    *(bf8*)&sBl[srow * GS + sk] = vbl;
    if constexpr (ALO) *(bf8*)&sAl[srow * GS + sk] = val_;
    __syncthreads();

    bf8 ah[2], al[2], bh[2], bl[2];
#pragma unroll
    for (int i = 0; i < 2; ++i) {
      ah[i] = *(bf8*)&sAh[(wm + i * 16 + fr) * GS + fq * 8];
      bh[i] = *(bf8*)&sBh[(wn + i * 16 + fr) * GS + fq * 8];
      bl[i] = *(bf8*)&sBl[(wn + i * 16 + fr) * GS + fq * 8];
      if constexpr (ALO) al[i] = *(bf8*)&sAl[(wm + i * 16 + fr) * GS + fq * 8];
    }
#pragma unroll
    for (int mi = 0; mi < 2; ++mi)
#pragma unroll
      for (int ni = 0; ni < 2; ++ni) {
        acc[mi][ni] = MFMA_BF16(ah[mi], bh[ni], acc[mi][ni], 0, 0, 0);
        acc[mi][ni] = MFMA_BF16(ah[mi], bl[ni], acc[mi][ni], 0, 0, 0);
        if constexpr (ALO) acc[mi][ni] = MFMA_BF16(al[mi], bh[ni], acc[mi][ni], 0, 0, 0);
      }
  }

  float* Cf = CfB ? CfB + br * sC : nullptr;
  short* Ch = ChB ? ChB + br * sC : nullptr;
  short* Cl = ClB ? ClB + br * sC : nullptr;
#pragma unroll
  for (int mi = 0; mi < 2; ++mi)
#pragma unroll
    for (int ni = 0; ni < 2; ++ni) {
      int cidx = bn + wn + ni * 16 + fr;
#pragma unroll
      for (int r = 0; r < 4; ++r) {
        size_t off = (size_t)(bm + wm + mi * 16 + fq * 4 + r) * Nn + cidx;
        float x = acc[mi][ni][r];
        if constexpr (EPI == 0) Cf[off] = x;
        if constexpr (EPI >= 1) {
          unsigned short h = f2bf(x);
          Ch[off] = (short)h;
          if constexpr (EPI == 2) Cl[off] = (short)f2bf(x - bf2f(h));
        }
      }
    }
}

// ---- spmm body (D=128, bf16 in, hi[+lo] out, MLP-8): sb in [0, 3072)
template <bool WLO>
__device__ void dev_spmm128(int sb, int tid,
    const int* __restrict__ colsB, const float* __restrict__ cvalsB,
    const int* __restrict__ cntB, const short* __restrict__ HinB,
    short* __restrict__ HhB, short* __restrict__ HlB) {
  const int br = sb >= 1536;
  const int bb = br ? sb - 1536 : sb;
  const int* cols = colsB + (size_t)br * NN * CAP;
  const float* cvals = cvalsB + (size_t)br * NN * CAP;
  const int* cnt = cntB + br * NN;
  const short* Hin = HinB + (size_t)br * NN * 128;
  int row = (bb * 256 + tid) >> 6;
  int lane = tid & 63;
  int c = cnt[row];
  const int base = row * CAP;
  float cv0 = 0.f, cv1 = 0.f;
  int j0 = 0, j1 = 0;
  if (lane < c) { j0 = cols[base + lane]; cv0 = cvals[base + lane]; }
  if (64 + lane < c) { j1 = cols[base + 64 + lane]; cv1 = cvals[base + 64 + lane]; }
  float2 acc = make_float2(0.f, 0.f);
  for (int k = 0; k < c; k += 8) {
    unsigned hv[8]; float cv[8];
#pragma unroll
    for (int u = 0; u < 8; ++u) {
      int kk = k + u;
      if (kk < c) {
        int jj = (kk & 64) ? j1 : j0;
        float cc = (kk & 64) ? cv1 : cv0;
        int j = __shfl(jj, kk & 63);
        cv[u] = __shfl(cc, kk & 63);
        hv[u] = *(const unsigned*)&Hin[(size_t)j * 128 + lane * 2];
      }
    }
#pragma unroll
    for (int u = 0; u < 8; ++u) {
      if (k + u < c) {
        acc.x += cv[u] * bf2f((unsigned short)(hv[u] & 0xffff));
        acc.y += cv[u] * bf2f((unsigned short)(hv[u] >> 16));
      }
    }
  }
  size_t o = (size_t)br * NN * 128 + (size_t)row * 128 + lane * 2;
  unsigned short hx = f2bf(acc.x), hy = f2bf(acc.y);
  *(unsigned*)&HhB[o] = (unsigned)hx | ((unsigned)hy << 16);
  if constexpr (WLO) {
    unsigned short lx = f2bf(acc.x - bf2f(hx)), ly = f2bf(acc.y - bf2f(hy));
    *(unsigned*)&HlB[o] = (unsigned)lx | ((unsigned)ly << 16);
  }
}

// ---- final body: fb in [0, 1536)
__device__ void dev_final(int fb, int tid,
    const float* __restrict__ H1e, const float* __restrict__ H2e,
    const float* __restrict__ mu, float* __restrict__ hf_out,
    float* __restrict__ q_out) {
  int row = (fb * 256 + tid) >> 6;
  int lane = tid & 63;
  float2 h1 = *(const float2*)&H1e[row * 128 + lane * 2];
  float2 h2 = *(const float2*)&H2e[row * 128 + lane * 2];
  float2 hf = make_float2(h1.x + h2.x, h1.y + h2.y);
  *(float2*)&hf_out[row * 128 + lane * 2] = hf;
  float d2[10];
#pragma unroll
  for (int k = 0; k < 10; ++k) {
    float dx = hf.x - mu[k * 128 + lane * 2];
    float dy = hf.y - mu[k * 128 + lane * 2 + 1];
    d2[k] = dx * dx + dy * dy;
  }
#pragma unroll
  for (int k = 0; k < 10; ++k)
#pragma unroll
    for (int o = 32; o; o >>= 1) d2[k] += __shfl_xor(d2[k], o);
  float q[10], s = 0.f;
#pragma unroll
  for (int k = 0; k < 10; ++k) { q[k] = 1.f / (1.f + d2[k]); s += q[k]; }
  float inv = 1.f / s;
  if (lane < 10) q_out[row * 10 + lane] = q[lane] * inv;
}

// ================================================================ kernels

// K1: sparsify [0,3072) | convw [3072,4352) | convX [4352,10496) | wc2 [10496,10528)
// All branches low-VGPR so sparsify keeps high occupancy (R9 lesson).
__global__ __launch_bounds__(256) void k1_prep(
    const float* A0, const float* A1, int* colsB, float* valsB, int* cntB,
    const float* W11, const float* W21, const float* W12, const float* W22,
    short* W1th, short* W1tl, short* W2th, short* W2tl,
    const float* X0, const float* X1, short* XhB,
    short* Wc2h, short* Wc2l) {
  __shared__ char smem[2 * 16 * 68 * 4];  // only wc2 blocks use it
  int bid = blockIdx.x, tid = threadIdx.x;
  if (bid < 3072) dev_sparsify(bid, tid, A0, A1, colsB, valsB, cntB);
  else if (bid < 4352) dev_convw(bid - 3072, tid, W11, W21, W12, W22,
                                 W1th, W1tl, W2th, W2tl);
  else if (bid < 10496) dev_convX(bid - 4352, tid, X0, X1, XhB);
  else dev_wc2(bid - 10496, tid, smem, W11, W12, W21, W22, Wc2h, Wc2l);
}

// K2 wrapper: standalone GEMM
template <bool ALO, int EPI>
__global__ __launch_bounds__(256) void gemm_nt(
    const short* AhB, const short* AlB, size_t sA,
    const short* BhB, const short* BlB, size_t sB,
    float* CfB, short* ChB, short* ClB, size_t sC, int K, int Nn) {
  __shared__ char smem[(ALO ? 4 : 3) * 64 * GS * 2];
  dev_gemm<ALO, EPI>(blockIdx.x, blockIdx.y, blockIdx.z, threadIdx.x, smem,
                     AhB, AlB, sA, BhB, BlB, sB, CfB, ChB, ClB, sC, K, Nn);
}

// K3: GEMM2 [0,384) | fvec1 [384,3456)
__global__ __launch_bounds__(256) void k3_gemm2_fvec(
    const short* H1h, const short* W2th, const short* W2tl, short* G1h,
    const float* v111, const float* v112, const float* v211, const float* v212,
    float* f1, float* f2) {
  __shared__ char smem[3 * 64 * GS * 2];
  int bid = blockIdx.x, tid = threadIdx.x;
  if (bid < 384) {
    int bx = bid % 96, r = bid / 96;
    int by = r & 1, br = r >> 1;
    dev_gemm<false, 1>(bx, by, br, tid, smem, H1h, nullptr, (size_t)NN * 256,
                       W2th, W2tl, (size_t)256 * 128, nullptr, G1h, nullptr,
                       (size_t)NN * 128, 256, 128);
  } else {
    dev_fvec256(bid - 384, tid, H1h, v111, v112, v211, v212, f1, f2);
  }
}

// K4/K5: fused GAT softmax + SPMM (MLP-8) + optional next-layer fvec epilogue
template <bool WF32, bool FUSE>
__global__ __launch_bounds__(256) void gatspmm_kernel(
    const int* __restrict__ colsB, const float* __restrict__ avalsB,
    const int* __restrict__ cntB, const float* __restrict__ f1B,
    const float* __restrict__ f2B, float* __restrict__ cvalsB,
    const short* __restrict__ HinB, float* __restrict__ HoutB,
    short* __restrict__ HhB,
    const float* __restrict__ nv10, const float* __restrict__ nv20,
    const float* __restrict__ nv11, const float* __restrict__ nv21,
    float* __restrict__ g1B, float* __restrict__ g2B) {
  const int br = blockIdx.y;
  const int* cols = colsB + (size_t)br * NN * CAP;
  const float* avals = avalsB + (size_t)br * NN * CAP;
  const int* cnt = cntB + br * NN;
  const float* f1 = f1B + br * NN;
  const float* f2 = f2B + br * NN;
  float* cvals = cvalsB + (size_t)br * NN * CAP;
  const short* Hin = HinB + (size_t)br * NN * 128;
  int row = (blockIdx.x * blockDim.x + threadIdx.x) >> 6;
  int lane = threadIdx.x & 63;
  int c = cnt[row];
  float f1i = f1[row];
  const int base = row * CAP;
  float e0 = 0.f, e1 = 0.f;
  int j0 = 0, j1 = 0;
  {
    int k = lane;
    if (k < c) {
      float a = avals[base + k];
      j0 = cols[base + k];
      float lg = a * (f1i + f2[j0]);
      e0 = expf(1.f / (1.f + expf(-lg)));
    }
    k = 64 + lane;
    if (k < c) {
      float a = avals[base + k];
      j1 = cols[base + k];
      float lg = a * (f1i + f2[j1]);
      e1 = expf(1.f / (1.f + expf(-lg)));
    }
  }
  float s = e0 + e1;
#pragma unroll
  for (int o = 32; o; o >>= 1) s += __shfl_xor(s, o);
  float inv = (s == 0.f) ? 1.f : 1.f / s;
  if (lane < c) cvals[base + lane] = e0 * inv;
  if (64 + lane < c) cvals[base + 64 + lane] = e1 * inv;

  float2 acc = make_float2(0.f, 0.f);
  for (int k = 0; k < c; k += 8) {
    unsigned hv[8]; float cv[8];
#pragma unroll
    for (int u = 0; u < 8; ++u) {
      int kk = k + u;
      if (kk < c) {
        int jj = (kk & 64) ? j1 : j0;
        float ee = (kk & 64) ? e1 : e0;
        int j = __shfl(jj, kk & 63);
        cv[u] = __shfl(ee, kk & 63) * inv;
        hv[u] = *(const unsigned*)&Hin[(size_t)j * 128 + lane * 2];
      }
    }
#pragma unroll
    for (int u = 0; u < 8; ++u) {
      if (k + u < c) {
        acc.x += cv[u] * bf2f((unsigned short)(hv[u] & 0xffff));
        acc.y += cv[u] * bf2f((unsigned short)(hv[u] >> 16));
      }
    }
  }
  size_t o = (size_t)br * NN * 128 + (size_t)row * 128 + lane * 2;
  if constexpr (WF32) *(float2*)&HoutB[o] = acc;
  unsigned hw = (unsigned)(unsigned short)f2bf(acc.x) | ((unsigned)f2bf(acc.y) << 16);
  *(unsigned*)&HhB[o] = hw;
  if constexpr (FUSE) {
    const float* w1 = br ? nv11 : nv10;
    const float* w2 = br ? nv21 : nv20;
    float s1 = acc.x * w1[lane * 2] + acc.y * w1[lane * 2 + 1];
    float s2 = acc.x * w2[lane * 2] + acc.y * w2[lane * 2 + 1];
#pragma unroll
    for (int o2 = 32; o2; o2 >>= 1) {
      s1 += __shfl_xor(s1, o2);
      s2 += __shfl_xor(s2, o2);
    }
    if (lane == 0) { g1B[br * NN + row] = s1; g2B[br * NN + row] = s2; }
  }
}

// K6: spmm C2s [0,3072) | final [3072,4608)
__global__ __launch_bounds__(256) void k6_spmm_final(
    const int* colsB, const float* c2v, const int* cntB,
    const short* Hech, short* C2sh,
    const float* H1e, const float* H2e, const float* mu,
    float* hf_out, float* q_out) {
  int bid = blockIdx.x, tid = threadIdx.x;
  if (bid < 3072) dev_spmm128<false>(bid, tid, colsB, c2v, cntB, Hech, C2sh, nullptr);
  else dev_final(bid - 3072, tid, H1e, H2e, mu, hf_out, q_out);
}

// K7: spmm Ct (hi+lo out)
__global__ __launch_bounds__(256) void spmm128hl_kernel(
    const int* colsB, const float* cvalsB, const int* cntB,
    const short* HinB, short* HhB, short* HlB) {
  dev_spmm128<true>(blockIdx.x + blockIdx.y * 1536, threadIdx.x,
                    colsB, cvalsB, cntB, HinB, HhB, HlB);
}

// ================================================================ host
extern "C" void kernel_launch(void* const* d_in, const int* in_sizes, int n_in,
                              void* d_out, int out_size, void* d_ws, size_t ws_size,
                              hipStream_t stream) {
  const int D0 = 512, D1 = 256, D2 = 128;
  const int S1 = D0 * D1, S2 = D1 * D2;
  float* out = (float*)d_out;
  const size_t o0 = 0;                       // H_F  [N,128]
  const size_t o1 = o0 + (size_t)NN * 128;   // q    [N,10]
  const size_t o2 = o1 + (size_t)NN * 10;    // H    [N,128]
  const size_t o3 = o2 + (size_t)NN * 128;   // H2   [N,128]
  const size_t o4 = o3 + (size_t)NN * 128;   // X_   [N,512]
  const size_t o5 = o4 + (size_t)NN * 512;   // X_2  [N,512]

  char* w = (char*)d_ws;
  auto alloc = [&](size_t bytes) -> void* {
    void* p = (void*)w;
    w += (bytes + 255) & ~(size_t)255;
    return p;
  };
  int*   cols  = (int*)  alloc((size_t)2 * NN * CAP * 4);
  float* avals = (float*)alloc((size_t)2 * NN * CAP * 4);
  float* c1v   = (float*)alloc((size_t)2 * NN * CAP * 4);
  float* c2v   = (float*)alloc((size_t)2 * NN * CAP * 4);
  int*   cnt   = (int*)  alloc((size_t)2 * NN * 4);
  float* f1    = (float*)alloc((size_t)2 * NN * 4);
  float* f2    = (float*)alloc((size_t)2 * NN * 4);
  float* g1    = (float*)alloc((size_t)2 * NN * 4);
  float* g2    = (float*)alloc((size_t)2 * NN * 4);
  short* Xh    = (short*)alloc((size_t)2 * NN * D0 * 2);
  short* H1h   = (short*)alloc((size_t)2 * NN * D1 * 2);
  short* G1h   = (short*)alloc((size_t)2 * NN * D2 * 2);
  short* H2h   = (short*)alloc((size_t)2 * NN * D2 * 2);
  short* Hech  = (short*)alloc((size_t)2 * NN * D2 * 2);
  short* C2sh  = (short*)alloc((size_t)2 * NN * D2 * 2);
  short* Cth   = (short*)alloc((size_t)2 * NN * D2 * 2);
  short* Ctl   = (short*)alloc((size_t)2 * NN * D2 * 2);
  short* W1th  = (short*)alloc((size_t)2 * S1 * 2);
  short* W1tl  = (short*)alloc((size_t)2 * S1 * 2);
  short* W2th  = (short*)alloc((size_t)2 * S2 * 2);
  short* W2tl  = (short*)alloc((size_t)2 * S2 * 2);
  short* Wc2h  = (short*)alloc((size_t)2 * 512 * 128 * 2);
  short* Wc2l  = (short*)alloc((size_t)2 * 512 * 128 * 2);

  const float* A   = (const float*)d_in[0];
  const float* A2  = (const float*)d_in[1];
  const float* X   = (const float*)d_in[2];
  const float* X2  = (const float*)d_in[3];
  const float* W11 = (const float*)d_in[4];
  const float* v111= (const float*)d_in[5];
  const float* v112= (const float*)d_in[6];
  const float* W12 = (const float*)d_in[7];
  const float* v121= (const float*)d_in[8];
  const float* v122= (const float*)d_in[9];
  const float* W21 = (const float*)d_in[10];
  const float* v211= (const float*)d_in[11];
  const float* v212= (const float*)d_in[12];
  const float* W22 = (const float*)d_in[13];
  const float* v221= (const float*)d_in[14];
  const float* v222= (const float*)d_in[15];
  const float* mu  = (const float*)d_in[16];

  const dim3 rows2(NN / 4, 2);

  // K1: sparsify || convw(T) || convX || Wc = W1@W2 (all low-VGPR)
  k1_prep<<<10528, 256, 0, stream>>>(
      A, A2, cols, avals, cnt, W11, W21, W12, W22,
      W1th, W1tl, W2th, W2tl, X, X2, Xh, Wc2h, Wc2l);
  // K2: H1 = X @ W11 (2-MFMA, out bf16-hi)
  gemm_nt<false, 1><<<dim3(NN / 64, D1 / 64, 2), 256, 0, stream>>>(
      Xh, nullptr, (size_t)NN * D0, W1th, W1tl, (size_t)S1,
      nullptr, H1h, nullptr, (size_t)NN * D1, D0, D1);
  // K3: G1 = H1 @ W12 (2-MFMA) || fvec1
  k3_gemm2_fvec<<<3456, 256, 0, stream>>>(
      H1h, W2th, W2tl, G1h, v111, v112, v211, v212, f1, f2);
  // K4: C1 + H2 = C1 @ G1 (bf16) + fused fvec2 -> g1/g2
  gatspmm_kernel<false, true><<<rows2, 256, 0, stream>>>(
      cols, avals, cnt, f1, f2, c1v, G1h, nullptr, H2h,
      v121, v122, v221, v222, g1, g2);
  // K5: C2 + Henc = C2 @ H2 -> out o2/o3 (f32) + bf16 copy
  gatspmm_kernel<true, false><<<rows2, 256, 0, stream>>>(
      cols, avals, cnt, g1, g2, c2v, H2h, out + o2, Hech,
      nullptr, nullptr, nullptr, nullptr, nullptr, nullptr);
  // K6: C2s = C2 @ Henc || final (H_F + q)
  k6_spmm_final<<<4608, 256, 0, stream>>>(
      cols, c2v, cnt, Hech, C2sh, out + o2, out + o3, mu, out + o0, out + o1);
  // K7: Ct = C1 @ C2s (hi+lo)
  spmm128hl_kernel<<<rows2, 256, 0, stream>>>(cols, c1v, cnt, C2sh, Cth, Ctl);
  // K8: X_ = Ct @ Wc^T (3-MFMA, K=128, f32 -> out o4/o5)  [Wc = W1@W2]
  gemm_nt<true, 0><<<dim3(NN / 64, D0 / 64, 2), 256, 0, stream>>>(
      Cth, Ctl, (size_t)NN * D2, Wc2h, Wc2l, (size_t)(512 * 128),
      out + o4, nullptr, nullptr, (size_t)NN * D0, D2, D0);
}

// Round 11
// 163.384 us; speedup vs baseline: 1.1213x; 1.0054x over previous
//
#include <hip/hip_runtime.h>
#include <hip/hip_bf16.h>

#define NN 6144
#define CAP 128

typedef short bf8 __attribute__((ext_vector_type(8)));
typedef float f4 __attribute__((ext_vector_type(4)));

__device__ inline unsigned short f2bf(float x) {
  union { float f; unsigned u; } v; v.f = x;
  unsigned r = v.u + 0x7fff + ((v.u >> 16) & 1);
  return (unsigned short)(r >> 16);
}
__device__ inline float bf2f(unsigned short b) {
  union { float f; unsigned u; } v; v.u = ((unsigned)b) << 16;
  return v.f;
}

// ================================================================ device bodies

// ---- sparsify (register MLP-6, nt loads, LDS-staged coalesced writes)
// bid in [0, 3072); smem: 1KB per wave (col[128] | val[128])
__device__ void dev_sparsify(int bid, int tid, char* smem,
    const float* __restrict__ A0, const float* __restrict__ A1,
    int* __restrict__ colsB, float* __restrict__ valsB, int* __restrict__ cntB) {
  const int br = bid >= 1536;
  const int bb = br ? bid - 1536 : bid;
  const float* __restrict__ A = br ? A1 : A0;
  int* cols = colsB + (size_t)br * NN * CAP;
  float* vals = valsB + (size_t)br * NN * CAP;
  int* cnt = cntB + br * NN;
  const int wv = tid >> 6, lane = tid & 63;
  const int row = bb * 4 + wv;
  int* colstage = (int*)(smem + wv * 1024);
  float* valstage = (float*)(smem + wv * 1024 + 512);
  const f4* __restrict__ arow = (const f4*)(A + (size_t)row * NN);
  int base = 0;
  for (int it = 0; it < 24; it += 6) {
    f4 v[6];
#pragma unroll
    for (int u = 0; u < 6; ++u) v[u] = __builtin_nontemporal_load(&arow[(it + u) * 64 + lane]);
#pragma unroll
    for (int u = 0; u < 6; ++u) {
      float xs[4] = {v[u][0], v[u][1], v[u][2], v[u][3]};
      unsigned long long m[4];
#pragma unroll
      for (int q = 0; q < 4; ++q) m[q] = __ballot(xs[q] != 0.0f);
      int off0 = base;
      int off1 = off0 + __popcll(m[0]);
      int off2 = off1 + __popcll(m[1]);
      int off3 = off2 + __popcll(m[2]);
      base = off3 + __popcll(m[3]);
      int offs[4] = {off0, off1, off2, off3};
      unsigned long long lmask = (1ull << lane) - 1ull;
#pragma unroll
      for (int q = 0; q < 4; ++q) {
        if (xs[q] != 0.0f) {
          int idx = offs[q] + __popcll(m[q] & lmask);
          if (idx < CAP) {          // bound: stay inside this wave's 1KB stage
            colstage[idx] = ((it + u) * 64 + lane) * 4 + q;
            valstage[idx] = xs[q];
          }
        }
      }
    }
  }
  __syncthreads();  // drain LDS scatters (all waves in a sparsify block reach this)
  const int rbase = row * CAP;
  // coalesced flush: 4x 256B contiguous stores (entries beyond cnt are unread)
  int c0 = colstage[lane], c1 = colstage[64 + lane];
  float v0 = valstage[lane], v1 = valstage[64 + lane];
  cols[rbase + lane] = c0;
  cols[rbase + 64 + lane] = c1;
  vals[rbase + lane] = v0;
  vals[rbase + 64 + lane] = v1;
  if (lane == 0) cnt[row] = base < CAP ? base : CAP;
}

// ---- weights -> hi/lo transposed: cb in [0, 1280)
__device__ void dev_convw(int cb, int tid,
    const float* __restrict__ W11, const float* __restrict__ W21,
    const float* __restrict__ W12, const float* __restrict__ W22,
    short* __restrict__ W1th, short* __restrict__ W1tl,
    short* __restrict__ W2th, short* __restrict__ W2tl) {
  const int S1 = 512 * 256, S2 = 256 * 128;
  int i = cb * 256 + tid;
  if (i < 2 * S1) {
    int br = i >= S1;
    int idx = br ? i - S1 : i;
    float x = (br ? W21 : W11)[idx];
    unsigned short h = f2bf(x), l = f2bf(x - bf2f(h));
    int r = idx / 256, c = idx % 256;
    size_t o = (size_t)br * S1;
    W1th[o + c * 512 + r] = (short)h; W1tl[o + c * 512 + r] = (short)l;
  } else {
    int i2 = i - 2 * S1;
    if (i2 >= 2 * S2) return;
    int br = i2 >= S2;
    int idx = br ? i2 - S2 : i2;
    float x = (br ? W22 : W12)[idx];
    unsigned short h = f2bf(x), l = f2bf(x - bf2f(h));
    int r = idx / 128, c = idx % 128;
    size_t o = (size_t)br * S2;
    W2th[o + c * 256 + r] = (short)h; W2tl[o + c * 256 + r] = (short)l;
  }
}

// ---- X -> bf16 hi: xb in [0, 6144)
__device__ void dev_convX(int xb, int tid,
    const float* __restrict__ X0, const float* __restrict__ X1,
    short* __restrict__ XhB) {
  const int br = xb >= 3072;
  const int b = br ? xb - 3072 : xb;
  const float* __restrict__ in = br ? X1 : X0;
  short* hi = XhB + (size_t)br * NN * 512;
  int i = b * 256 + tid;
  float4 v = *(const float4*)&in[i * 4];
  short4 h;
  h.x = (short)f2bf(v.x);
  h.y = (short)f2bf(v.y);
  h.z = (short)f2bf(v.z);
  h.w = (short)f2bf(v.w);
  *(short4*)&hi[i * 4] = h;
}

// ---- Wc = W1 @ W2 -> hi/lo, wb in [0, 32)
__device__ void dev_wc2(int wb, int tid, char* smemc,
    const float* __restrict__ W11, const float* __restrict__ W12,
    const float* __restrict__ W21, const float* __restrict__ W22,
    short* __restrict__ Wch, short* __restrict__ Wcl) {
  const int bx = wb & 7, by = (wb >> 3) & 1, br = wb >> 4;
  const float* W1 = br ? W21 : W11;
  const float* W2 = br ? W22 : W12;
  short* Ch = Wch + (size_t)br * 512 * 128;
  short* Cl = Wcl + (size_t)br * 512 * 128;
  float (*As)[68] = (float(*)[68])smemc;
  float (*Bs)[68] = (float(*)[68])(smemc + 16 * 68 * 4);
  const int bm = bx * 64, bn = by * 64;
  const int t = tid;
  const int tm = (t >> 4) * 4, tn = (t & 15) * 4;
  const int la_m = t >> 2, la_k = (t & 3) * 4;
  const int lb_k = t >> 4, lb_n = (t & 15) * 4;
  float acc[4][4] = {};
  for (int k0 = 0; k0 < 256; k0 += 16) {
    float4 a4 = *(const float4*)&W1[(size_t)(bm + la_m) * 256 + k0 + la_k];
    float4 b4 = *(const float4*)&W2[(size_t)(k0 + lb_k) * 128 + bn + lb_n];
    __syncthreads();
    As[la_k + 0][la_m] = a4.x;
    As[la_k + 1][la_m] = a4.y;
    As[la_k + 2][la_m] = a4.z;
    As[la_k + 3][la_m] = a4.w;
    Bs[lb_k][lb_n + 0] = b4.x;
    Bs[lb_k][lb_n + 1] = b4.y;
    Bs[lb_k][lb_n + 2] = b4.z;
    Bs[lb_k][lb_n + 3] = b4.w;
    __syncthreads();
#pragma unroll
    for (int k = 0; k < 16; ++k) {
      float a0 = As[k][tm + 0], a1 = As[k][tm + 1], a2 = As[k][tm + 2], a3 = As[k][tm + 3];
      float b0 = Bs[k][tn + 0], b1 = Bs[k][tn + 1], b2 = Bs[k][tn + 2], b3 = Bs[k][tn + 3];
      acc[0][0] += a0 * b0; acc[0][1] += a0 * b1; acc[0][2] += a0 * b2; acc[0][3] += a0 * b3;
      acc[1][0] += a1 * b0; acc[1][1] += a1 * b1; acc[1][2] += a1 * b2; acc[1][3] += a1 * b3;
      acc[2][0] += a2 * b0; acc[2][1] += a2 * b1; acc[2][2] += a2 * b2; acc[2][3] += a2 * b3;
      acc[3][0] += a3 * b0; acc[3][1] += a3 * b1; acc[3][2] += a3 * b2; acc[3][3] += a3 * b3;
    }
  }
#pragma unroll
  for (int i = 0; i < 4; ++i)
#pragma unroll
    for (int j = 0; j < 4; ++j) {
      float x = acc[i][j];
      size_t off = (size_t)(bm + tm + i) * 128 + bn + tn + j;
      unsigned short h = f2bf(x);
      Ch[off] = (short)h;
      Cl[off] = (short)f2bf(x - bf2f(h));
    }
}

// ---- fvec (layer 1, D=256, bf16 input): fb in [0, 3072)
__device__ void dev_fvec256(int fb, int tid,
    const short* __restrict__ HB, const float* __restrict__ v10,
    const float* __restrict__ v20, const float* __restrict__ v11,
    const float* __restrict__ v21, float* __restrict__ f1B, float* __restrict__ f2B) {
  const int br = fb >= 1536;
  const int bb = br ? fb - 1536 : fb;
  const short* H = HB + (size_t)br * NN * 256;
  const float* v1 = br ? v11 : v10;
  const float* v2 = br ? v21 : v20;
  float* f1 = f1B + br * NN;
  float* f2 = f2B + br * NN;
  int row = (bb * 256 + tid) >> 6;
  int lane = tid & 63;
  const short* hp = H + (size_t)row * 256 + lane * 4;
  float s1 = 0.f, s2 = 0.f;
#pragma unroll
  for (int e = 0; e < 4; ++e) {
    float h = bf2f((unsigned short)hp[e]);
    s1 += h * v1[lane * 4 + e];
    s2 += h * v2[lane * 4 + e];
  }
#pragma unroll
  for (int o = 32; o; o >>= 1) {
    s1 += __shfl_xor(s1, o);
    s2 += __shfl_xor(s2, o);
  }
  if (lane == 0) { f1[row] = s1; f2[row] = s2; }
}

// ---- split-bf16 MFMA GEMM (NT) tile body; smem >= (ALO?4:3)*5120 bytes
#define GS 40
#define MFMA_BF16 __builtin_amdgcn_mfma_f32_16x16x32_bf16

template <bool ALO, int EPI>  // EPI 0: f32, 1: bf16-hi, 2: hi+lo
__device__ void dev_gemm(int bx, int by, int br, int tid, char* smemc,
    const short* __restrict__ AhB, const short* __restrict__ AlB, size_t sA,
    const short* __restrict__ BhB, const short* __restrict__ BlB, size_t sB,
    float* __restrict__ CfB, short* __restrict__ ChB, short* __restrict__ ClB,
    size_t sC, int K, int Nn) {
  short* sAh = (short*)smemc;
  short* sBh = sAh + 64 * GS;
  short* sBl = sBh + 64 * GS;
  short* sAl = sBl + 64 * GS;  // used only if ALO
  const short* Ahg = AhB + br * sA;
  const short* Bhg = BhB + br * sB;
  const short* Blg = BlB + br * sB;
  const int bm = bx * 64, bn = by * 64;
  const int t = tid;
  const int lane = t & 63, w = t >> 6;
  const int wm = (w & 1) * 32, wn = (w >> 1) * 32;
  const int fr = lane & 15, fq = lane >> 4;
  const int srow = t >> 2, sk = (t & 3) * 8;

  f4 acc[2][2] = {};

  for (int k0 = 0; k0 < K; k0 += 32) {
    const size_t aoff = (size_t)(bm + srow) * K + k0 + sk;
    const size_t boff = (size_t)(bn + srow) * K + k0 + sk;
    bf8 vah = *(const bf8*)&Ahg[aoff];
    bf8 vbh = *(const bf8*)&Bhg[boff];
    bf8 vbl = *(const bf8*)&Blg[boff];
    bf8 val_;
    if constexpr (ALO) val_ = *(const bf8*)&(AlB + br * sA)[aoff];
    __syncthreads();
    *(bf8*)&sAh[srow * GS + sk] = vah;
    *(bf8*)&sBh[srow * GS + sk] = vbh;
    *(bf8*)&sBl[srow * GS + sk] = vbl;
    if constexpr (ALO) *(bf8*)&sAl[srow * GS + sk] = val_;
    __syncthreads();

    bf8 ah[2], al[2], bh[2], bl[2];
#pragma unroll
    for (int i = 0; i < 2; ++i) {
      ah[i] = *(bf8*)&sAh[(wm + i * 16 + fr) * GS + fq * 8];
      bh[i] = *(bf8*)&sBh[(wn + i * 16 + fr) * GS + fq * 8];
      bl[i] = *(bf8*)&sBl[(wn + i * 16 + fr) * GS + fq * 8];
      if constexpr (ALO) al[i] = *(bf8*)&sAl[(wm + i * 16 + fr) * GS + fq * 8];
    }
#pragma unroll
    for (int mi = 0; mi < 2; ++mi)
#pragma unroll
      for (int ni = 0; ni < 2; ++ni) {
        acc[mi][ni] = MFMA_BF16(ah[mi], bh[ni], acc[mi][ni], 0, 0, 0);
        acc[mi][ni] = MFMA_BF16(ah[mi], bl[ni], acc[mi][ni], 0, 0, 0);
        if constexpr (ALO) acc[mi][ni] = MFMA_BF16(al[mi], bh[ni], acc[mi][ni], 0, 0, 0);
      }
  }

  float* Cf = CfB ? CfB + br * sC : nullptr;
  short* Ch = ChB ? ChB + br * sC : nullptr;
  short* Cl = ClB ? ClB + br * sC : nullptr;
#pragma unroll
  for (int mi = 0; mi < 2; ++mi)
#pragma unroll
    for (int ni = 0; ni < 2; ++ni) {
      int cidx = bn + wn + ni * 16 + fr;
#pragma unroll
      for (int r = 0; r < 4; ++r) {
        size_t off = (size_t)(bm + wm + mi * 16 + fq * 4 + r) * Nn + cidx;
        float x = acc[mi][ni][r];
        if constexpr (EPI == 0) Cf[off] = x;
        if constexpr (EPI >= 1) {
          unsigned short h = f2bf(x);
          Ch[off] = (short)h;
          if constexpr (EPI == 2) Cl[off] = (short)f2bf(x - bf2f(h));
        }
      }
    }
}

// ---- spmm body (D=128, bf16 in, hi[+lo] out, MLP-8): sb in [0, 3072)
template <bool WLO>
__device__ void dev_spmm128(int sb, int tid,
    const int* __restrict__ colsB, const float* __restrict__ cvalsB,
    const int* __restrict__ cntB, const short* __restrict__ HinB,
    short* __restrict__ HhB, short* __restrict__ HlB) {
  const int br = sb >= 1536;
  const int bb = br ? sb - 1536 : sb;
  const int* cols = colsB + (size_t)br * NN * CAP;
  const float* cvals = cvalsB + (size_t)br * NN * CAP;
  const int* cnt = cntB + br * NN;
  const short* Hin = HinB + (size_t)br * NN * 128;
  int row = (bb * 256 + tid) >> 6;
  int lane = tid & 63;
  int c = cnt[row];
  const int base = row * CAP;
  float cv0 = 0.f, cv1 = 0.f;
  int j0 = 0, j1 = 0;
  if (lane < c) { j0 = cols[base + lane]; cv0 = cvals[base + lane]; }
  if (64 + lane < c) { j1 = cols[base + 64 + lane]; cv1 = cvals[base + 64 + lane]; }
  float2 acc = make_float2(0.f, 0.f);
  for (int k = 0; k < c; k += 8) {
    unsigned hv[8]; float cv[8];
#pragma unroll
    for (int u = 0; u < 8; ++u) {
      int kk = k + u;
      if (kk < c) {
        int jj = (kk & 64) ? j1 : j0;
        float cc = (kk & 64) ? cv1 : cv0;
        int j = __shfl(jj, kk & 63);
        cv[u] = __shfl(cc, kk & 63);
        hv[u] = *(const unsigned*)&Hin[(size_t)j * 128 + lane * 2];
      }
    }
#pragma unroll
    for (int u = 0; u < 8; ++u) {
      if (k + u < c) {
        acc.x += cv[u] * bf2f((unsigned short)(hv[u] & 0xffff));
        acc.y += cv[u] * bf2f((unsigned short)(hv[u] >> 16));
      }
    }
  }
  size_t o = (size_t)br * NN * 128 + (size_t)row * 128 + lane * 2;
  unsigned short hx = f2bf(acc.x), hy = f2bf(acc.y);
  *(unsigned*)&HhB[o] = (unsigned)hx | ((unsigned)hy << 16);
  if constexpr (WLO) {
    unsigned short lx = f2bf(acc.x - bf2f(hx)), ly = f2bf(acc.y - bf2f(hy));
    *(unsigned*)&HlB[o] = (unsigned)lx | ((unsigned)ly << 16);
  }
}

// ---- final body: fb in [0, 1536)
__device__ void dev_final(int fb, int tid,
    const float* __restrict__ H1e, const float* __restrict__ H2e,
    const float* __restrict__ mu, float* __restrict__ hf_out,
    float* __restrict__ q_out) {
  int row = (fb * 256 + tid) >> 6;
  int lane = tid & 63;
  float2 h1 = *(const float2*)&H1e[row * 128 + lane * 2];
  float2 h2 = *(const float2*)&H2e[row * 128 + lane * 2];
  float2 hf = make_float2(h1.x + h2.x, h1.y + h2.y);
  *(float2*)&hf_out[row * 128 + lane * 2] = hf;
  float d2[10];
#pragma unroll
  for (int k = 0; k < 10; ++k) {
    float dx = hf.x - mu[k * 128 + lane * 2];
    float dy = hf.y - mu[k * 128 + lane * 2 + 1];
    d2[k] = dx * dx + dy * dy;
  }
#pragma unroll
  for (int k = 0; k < 10; ++k)
#pragma unroll
    for (int o = 32; o; o >>= 1) d2[k] += __shfl_xor(d2[k], o);
  float q[10], s = 0.f;
#pragma unroll
  for (int k = 0; k < 10; ++k) { q[k] = 1.f / (1.f + d2[k]); s += q[k]; }
  float inv = 1.f / s;
  if (lane < 10) q_out[row * 10 + lane] = q[lane] * inv;
}

// ================================================================ kernels

// K0: convw [0,1280) | convX [1280,7424)  (feeds K1's GEMM1)
__global__ __launch_bounds__(256) void k0_prep(
    const float* W11, const float* W21, const float* W12, const float* W22,
    short* W1th, short* W1tl, short* W2th, short* W2tl,
    const float* X0, const float* X1, short* XhB) {
  int bid = blockIdx.x, tid = threadIdx.x;
  if (bid < 1280) dev_convw(bid, tid, W11, W21, W12, W22, W1th, W1tl, W2th, W2tl);
  else dev_convX(bid - 1280, tid, X0, X1, XhB);
}

// K1: sparsify [0,3072) | GEMM1 [3072,3840) | wc2 [3840,3872)
__global__ __launch_bounds__(256) void k1_main(
    const float* A0, const float* A1, int* colsB, float* valsB, int* cntB,
    const short* Xh, const short* W1th, const short* W1tl, short* H1h,
    const float* W11, const float* W12, const float* W21, const float* W22,
    short* Wc2h, short* Wc2l) {
  __shared__ char smem[15360];
  int bid = blockIdx.x, tid = threadIdx.x;
  if (bid < 3072) {
    dev_sparsify(bid, tid, smem, A0, A1, colsB, valsB, cntB);
  } else if (bid < 3840) {
    int g = bid - 3072;               // 96 x 4 x 2
    int bx = g % 96, r = g / 96;
    int by = r & 3, brz = r >> 2;
    dev_gemm<false, 1>(bx, by, brz, tid, smem, Xh, nullptr, (size_t)NN * 512,
                       W1th, W1tl, (size_t)512 * 256, nullptr, H1h, nullptr,
                       (size_t)NN * 256, 512, 256);
  } else {
    dev_wc2(bid - 3840, tid, smem, W11, W12, W21, W22, Wc2h, Wc2l);
  }
}

// K2 wrapper: standalone GEMM
template <bool ALO, int EPI>
__global__ __launch_bounds__(256) void gemm_nt(
    const short* AhB, const short* AlB, size_t sA,
    const short* BhB, const short* BlB, size_t sB,
    float* CfB, short* ChB, short* ClB, size_t sC, int K, int Nn) {
  __shared__ char smem[(ALO ? 4 : 3) * 64 * GS * 2];
  dev_gemm<ALO, EPI>(blockIdx.x, blockIdx.y, blockIdx.z, threadIdx.x, smem,
                     AhB, AlB, sA, BhB, BlB, sB, CfB, ChB, ClB, sC, K, Nn);
}

// K3: GEMM2 [0,384) | fvec1 [384,3456)
__global__ __launch_bounds__(256) void k3_gemm2_fvec(
    const short* H1h, const short* W2th, const short* W2tl, short* G1h,
    const float* v111, const float* v112, const float* v211, const float* v212,
    float* f1, float* f2) {
  __shared__ char smem[3 * 64 * GS * 2];
  int bid = blockIdx.x, tid = threadIdx.x;
  if (bid < 384) {
    int bx = bid % 96, r = bid / 96;
    int by = r & 1, br = r >> 1;
    dev_gemm<false, 1>(bx, by, br, tid, smem, H1h, nullptr, (size_t)NN * 256,
                       W2th, W2tl, (size_t)256 * 128, nullptr, G1h, nullptr,
                       (size_t)NN * 128, 256, 128);
  } else {
    dev_fvec256(bid - 384, tid, H1h, v111, v112, v211, v212, f1, f2);
  }
}

// K4/K5: fused GAT softmax + SPMM (MLP-8) + optional next-layer fvec epilogue
template <bool WF32, bool FUSE>
__global__ __launch_bounds__(256) void gatspmm_kernel(
    const int* __restrict__ colsB, const float* __restrict__ avalsB,
    const int* __restrict__ cntB, const float* __restrict__ f1B,
    const float* __restrict__ f2B, float* __restrict__ cvalsB,
    const short* __restrict__ HinB, float* __restrict__ HoutB,
    short* __restrict__ HhB,
    const float* __restrict__ nv10, const float* __restrict__ nv20,
    const float* __restrict__ nv11, const float* __restrict__ nv21,
    float* __restrict__ g1B, float* __restrict__ g2B) {
  const int br = blockIdx.y;
  const int* cols = colsB + (size_t)br * NN * CAP;
  const float* avals = avalsB + (size_t)br * NN * CAP;
  const int* cnt = cntB + br * NN;
  const float* f1 = f1B + br * NN;
  const float* f2 = f2B + br * NN;
  float* cvals = cvalsB + (size_t)br * NN * CAP;
  const short* Hin = HinB + (size_t)br * NN * 128;
  int row = (blockIdx.x * blockDim.x + threadIdx.x) >> 6;
  int lane = threadIdx.x & 63;
  int c = cnt[row];
  float f1i = f1[row];
  const int base = row * CAP;
  float e0 = 0.f, e1 = 0.f;
  int j0 = 0, j1 = 0;
  {
    int k = lane;
    if (k < c) {
      float a = avals[base + k];
      j0 = cols[base + k];
      float lg = a * (f1i + f2[j0]);
      e0 = expf(1.f / (1.f + expf(-lg)));
    }
    k = 64 + lane;
    if (k < c) {
      float a = avals[base + k];
      j1 = cols[base + k];
      float lg = a * (f1i + f2[j1]);
      e1 = expf(1.f / (1.f + expf(-lg)));
    }
  }
  float s = e0 + e1;
#pragma unroll
  for (int o = 32; o; o >>= 1) s += __shfl_xor(s, o);
  float inv = (s == 0.f) ? 1.f : 1.f / s;
  if (lane < c) cvals[base + lane] = e0 * inv;
  if (64 + lane < c) cvals[base + 64 + lane] = e1 * inv;

  float2 acc = make_float2(0.f, 0.f);
  for (int k = 0; k < c; k += 8) {
    unsigned hv[8]; float cv[8];
#pragma unroll
    for (int u = 0; u < 8; ++u) {
      int kk = k + u;
      if (kk < c) {
        int jj = (kk & 64) ? j1 : j0;
        float ee = (kk & 64) ? e1 : e0;
        int j = __shfl(jj, kk & 63);
        cv[u] = __shfl(ee, kk & 63) * inv;
        hv[u] = *(const unsigned*)&Hin[(size_t)j * 128 + lane * 2];
      }
    }
#pragma unroll
    for (int u = 0; u < 8; ++u) {
      if (k + u < c) {
        acc.x += cv[u] * bf2f((unsigned short)(hv[u] & 0xffff));
        acc.y += cv[u] * bf2f((unsigned short)(hv[u] >> 16));
      }
    }
  }
  size_t o = (size_t)br * NN * 128 + (size_t)row * 128 + lane * 2;
  if constexpr (WF32) *(float2*)&HoutB[o] = acc;
  unsigned hw = (unsigned)(unsigned short)f2bf(acc.x) | ((unsigned)f2bf(acc.y) << 16);
  *(unsigned*)&HhB[o] = hw;
  if constexpr (FUSE) {
    const float* w1 = br ? nv11 : nv10;
    const float* w2 = br ? nv21 : nv20;
    float s1 = acc.x * w1[lane * 2] + acc.y * w1[lane * 2 + 1];
    float s2 = acc.x * w2[lane * 2] + acc.y * w2[lane * 2 + 1];
#pragma unroll
    for (int o2 = 32; o2; o2 >>= 1) {
      s1 += __shfl_xor(s1, o2);
      s2 += __shfl_xor(s2, o2);
    }
    if (lane == 0) { g1B[br * NN + row] = s1; g2B[br * NN + row] = s2; }
  }
}

// K6: spmm C2s [0,3072) | final [3072,4608)
__global__ __launch_bounds__(256) void k6_spmm_final(
    const int* colsB, const float* c2v, const int* cntB,
    const short* Hech, short* C2sh,
    const float* H1e, const float* H2e, const float* mu,
    float* hf_out, float* q_out) {
  int bid = blockIdx.x, tid = threadIdx.x;
  if (bid < 3072) dev_spmm128<false>(bid, tid, colsB, c2v, cntB, Hech, C2sh, nullptr);
  else dev_final(bid - 3072, tid, H1e, H2e, mu, hf_out, q_out);
}

// K7: spmm Ct (hi+lo out)
__global__ __launch_bounds__(256) void spmm128hl_kernel(
    const int* colsB, const float* cvalsB, const int* cntB,
    const short* HinB, short* HhB, short* HlB) {
  dev_spmm128<true>(blockIdx.x + blockIdx.y * 1536, threadIdx.x,
                    colsB, cvalsB, cntB, HinB, HhB, HlB);
}

// ================================================================ host
extern "C" void kernel_launch(void* const* d_in, const int* in_sizes, int n_in,
                              void* d_out, int out_size, void* d_ws, size_t ws_size,
                              hipStream_t stream) {
  const int D0 = 512, D1 = 256, D2 = 128;
  const int S1 = D0 * D1, S2 = D1 * D2;
  float* out = (float*)d_out;
  const size_t o0 = 0;                       // H_F  [N,128]
  const size_t o1 = o0 + (size_t)NN * 128;   // q    [N,10]
  const size_t o2 = o1 + (size_t)NN * 10;    // H    [N,128]
  const size_t o3 = o2 + (size_t)NN * 128;   // H2   [N,128]
  const size_t o4 = o3 + (size_t)NN * 128;   // X_   [N,512]
  const size_t o5 = o4 + (size_t)NN * 512;   // X_2  [N,512]

  char* w = (char*)d_ws;
  auto alloc = [&](size_t bytes) -> void* {
    void* p = (void*)w;
    w += (bytes + 255) & ~(size_t)255;
    return p;
  };
  int*   cols  = (int*)  alloc((size_t)2 * NN * CAP * 4);
  float* avals = (float*)alloc((size_t)2 * NN * CAP * 4);
  float* c1v   = (float*)alloc((size_t)2 * NN * CAP * 4);
  float* c2v   = (float*)alloc((size_t)2 * NN * CAP * 4);
  int*   cnt   = (int*)  alloc((size_t)2 * NN * 4);
  float* f1    = (float*)alloc((size_t)2 * NN * 4);
  float* f2    = (float*)alloc((size_t)2 * NN * 4);
  float* g1    = (float*)alloc((size_t)2 * NN * 4);
  float* g2    = (float*)alloc((size_t)2 * NN * 4);
  short* Xh    = (short*)alloc((size_t)2 * NN * D0 * 2);
  short* H1h   = (short*)alloc((size_t)2 * NN * D1 * 2);
  short* G1h   = (short*)alloc((size_t)2 * NN * D2 * 2);
  short* H2h   = (short*)alloc((size_t)2 * NN * D2 * 2);
  short* Hech  = (short*)alloc((size_t)2 * NN * D2 * 2);
  short* C2sh  = (short*)alloc((size_t)2 * NN * D2 * 2);
  short* Cth   = (short*)alloc((size_t)2 * NN * D2 * 2);
  short* Ctl   = (short*)alloc((size_t)2 * NN * D2 * 2);
  short* W1th  = (short*)alloc((size_t)2 * S1 * 2);
  short* W1tl  = (short*)alloc((size_t)2 * S1 * 2);
  short* W2th  = (short*)alloc((size_t)2 * S2 * 2);
  short* W2tl  = (short*)alloc((size_t)2 * S2 * 2);
  short* Wc2h  = (short*)alloc((size_t)2 * 512 * 128 * 2);
  short* Wc2l  = (short*)alloc((size_t)2 * 512 * 128 * 2);

  const float* A   = (const float*)d_in[0];
  const float* A2  = (const float*)d_in[1];
  const float* X   = (const float*)d_in[2];
  const float* X2  = (const float*)d_in[3];
  const float* W11 = (const float*)d_in[4];
  const float* v111= (const float*)d_in[5];
  const float* v112= (const float*)d_in[6];
  const float* W12 = (const float*)d_in[7];
  const float* v121= (const float*)d_in[8];
  const float* v122= (const float*)d_in[9];
  const float* W21 = (const float*)d_in[10];
  const float* v211= (const float*)d_in[11];
  const float* v212= (const float*)d_in[12];
  const float* W22 = (const float*)d_in[13];
  const float* v221= (const float*)d_in[14];
  const float* v222= (const float*)d_in[15];
  const float* mu  = (const float*)d_in[16];

  const dim3 rows2(NN / 4, 2);

  // K0: convw + convX (GEMM1's inputs)
  k0_prep<<<7424, 256, 0, stream>>>(
      W11, W21, W12, W22, W1th, W1tl, W2th, W2tl, X, X2, Xh);
  // K1: sparsify (LDS-staged writes) || GEMM1 (H1 = X @ W11) || Wc = W1@W2
  k1_main<<<3872, 256, 0, stream>>>(
      A, A2, cols, avals, cnt, Xh, W1th, W1tl, H1h,
      W11, W12, W21, W22, Wc2h, Wc2l);
  // K3: G1 = H1 @ W12 (2-MFMA) || fvec1
  k3_gemm2_fvec<<<3456, 256, 0, stream>>>(
      H1h, W2th, W2tl, G1h, v111, v112, v211, v212, f1, f2);
  // K4: C1 + H2 = C1 @ G1 (bf16) + fused fvec2 -> g1/g2
  gatspmm_kernel<false, true><<<rows2, 256, 0, stream>>>(
      cols, avals, cnt, f1, f2, c1v, G1h, nullptr, H2h,
      v121, v122, v221, v222, g1, g2);
  // K5: C2 + Henc = C2 @ H2 -> out o2/o3 (f32) + bf16 copy
  gatspmm_kernel<true, false><<<rows2, 256, 0, stream>>>(
      cols, avals, cnt, g1, g2, c2v, H2h, out + o2, Hech,
      nullptr, nullptr, nullptr, nullptr, nullptr, nullptr);
  // K6: C2s = C2 @ Henc || final (H_F + q)
  k6_spmm_final<<<4608, 256, 0, stream>>>(
      cols, c2v, cnt, Hech, C2sh, out + o2, out + o3, mu, out + o0, out + o1);
  // K7: Ct = C1 @ C2s (hi+lo)
  spmm128hl_kernel<<<rows2, 256, 0, stream>>>(cols, c1v, cnt, C2sh, Cth, Ctl);
  // K8: X_ = Ct @ Wc^T (3-MFMA, K=128, f32 -> out o4/o5)
  gemm_nt<true, 0><<<dim3(NN / 64, D0 / 64, 2), 256, 0, stream>>>(
      Cth, Ctl, (size_t)NN * D2, Wc2h, Wc2l, (size_t)(512 * 128),
      out + o4, nullptr, nullptr, (size_t)NN * D0, D2, D0);
}